// Round 20
// baseline (175.833 us; speedup 1.0000x reference)
//
#include <hip/hip_runtime.h>
#include <hip/hip_fp16.h>

#define NN     100000
#define NE     1600000
#define FEAT   128
#define HID    64
#define OUTD   40
#define BNODES 32                         // aggregation bucket = 32 dst nodes
#define NSB    ((NN + 255) / 256)         // 391 superbuckets of 256 nodes
#define NBAGG  (NSB * 8)                  // 3128 aggregation buckets
#define CAP    5120                       // superbucket capacity (mean 4096, sd ~64)
#define CCHUNK 4096                       // edges per block in pair-scatter (mult of 4)
#define S1     4096.0f                    // h1s fixed-point scale (2^12)
#define S1INV  (1.0f / 4096.0f)
#define S2     2048.0f                    // hhs fixed-point scale (2^11)
#define S2INV  (1.0f / 2048.0f)

typedef _Float16 half8 __attribute__((ext_vector_type(8)));
typedef float    f32x4 __attribute__((ext_vector_type(4)));

// ---- A. scatter packed ex=(src<<8|dl) into superbucket segments (int4 loads) ----
__global__ __launch_bounds__(256) void k_pairs(const int* __restrict__ src,
                                               const int* __restrict__ dst,
                                               int* __restrict__ bfill,
                                               int* __restrict__ pairs) {
    __shared__ int bcnt[NSB];
    __shared__ int gb[NSB];
    int t = threadIdx.x;
    for (int i = t; i < NSB; i += 256) bcnt[i] = 0;
    __syncthreads();
    const int4* d4p = (const int4*)dst;
    const int4* s4p = (const int4*)src;
    int q0 = blockIdx.x * (CCHUNK / 4);
    int4 dv[4], sv[4];
    int off[16];
    #pragma unroll
    for (int i = 0; i < 4; ++i) {
        int q = q0 + i * 256 + t;
        if (q < NE / 4) {
            dv[i] = d4p[q];
            sv[i] = s4p[q];
            off[i*4+0] = atomicAdd(&bcnt[dv[i].x >> 8], 1);
            off[i*4+1] = atomicAdd(&bcnt[dv[i].y >> 8], 1);
            off[i*4+2] = atomicAdd(&bcnt[dv[i].z >> 8], 1);
            off[i*4+3] = atomicAdd(&bcnt[dv[i].w >> 8], 1);
        } else dv[i].x = -1;
    }
    __syncthreads();
    for (int i = t; i < NSB; i += 256) {
        int c = bcnt[i];
        gb[i] = c ? (i * CAP + atomicAdd(&bfill[i], c)) : 0;
    }
    __syncthreads();
    #pragma unroll
    for (int i = 0; i < 4; ++i) {
        if (dv[i].x >= 0) {
            pairs[gb[dv[i].x >> 8] + off[i*4+0]] = (sv[i].x << 8) | (dv[i].x & 255);
            pairs[gb[dv[i].y >> 8] + off[i*4+1]] = (sv[i].y << 8) | (dv[i].y & 255);
            pairs[gb[dv[i].z >> 8] + off[i*4+2]] = (sv[i].z << 8) | (dv[i].z & 255);
            pairs[gb[dv[i].w >> 8] + off[i*4+3]] = (sv[i].w << 8) | (dv[i].w & 255);
        }
    }
}

// ---- B. per-superbucket counting sort by (subbucket, src-stripe) + per-node dinv ----
__global__ __launch_bounds__(256) void k_csr(const int* __restrict__ pairs,
                                             const int* __restrict__ bfill,
                                             int* __restrict__ sb_beg,
                                             int* __restrict__ sb_cnt,
                                             int* __restrict__ csr,
                                             float* __restrict__ dinv) {
    __shared__ int hist[2048];
    __shared__ int exs[2048];
    __shared__ int nd[256];
    __shared__ int part[256];
    __shared__ int poff[9];
    __shared__ int sstart[8];
    __shared__ int dtot[8];
    int b = blockIdx.x, t = threadIdx.x;
    #pragma unroll
    for (int k = 0; k < 8; ++k) hist[t * 8 + k] = 0;
    nd[t] = 0;
    __syncthreads();
    int base = b * CAP, count = bfill[b];
    for (int i = t; i < count; i += 256) {
        int p = pairs[base + i];
        int key = (((p & 255) >> 5) << 8) | ((p >> 17) & 255);
        atomicAdd(&hist[key], 1);
        atomicAdd(&nd[p & 255], 1);
    }
    __syncthreads();
    {
        int node = (b << 8) + t;
        if (node < NN) dinv[node] = rsqrtf((float)nd[t] + 1.0f);
    }
    int loc[8], s0 = 0;
    #pragma unroll
    for (int k = 0; k < 8; ++k) { loc[k] = s0; s0 += hist[t * 8 + k]; }
    part[t] = s0;
    __syncthreads();
    for (int off = 1; off < 256; off <<= 1) {
        int u = (t >= off) ? part[t - off] : 0;
        __syncthreads();
        part[t] += u;
        __syncthreads();
    }
    int pex = part[t] - s0;
    #pragma unroll
    for (int k = 0; k < 8; ++k) exs[t * 8 + k] = pex + loc[k];
    __syncthreads();
    if (t < 8) {
        sstart[t] = exs[t * 256];
        int end = (t == 7) ? count : exs[(t + 1) * 256];
        dtot[t] = end - sstart[t];
    }
    __syncthreads();
    if (t == 0) {
        poff[0] = 0;
        for (int d = 0; d < 8; ++d) poff[d + 1] = poff[d] + ((dtot[d] + 31) & ~31);
    }
    __syncthreads();
    #pragma unroll
    for (int k = 0; k < 8; ++k) {
        int key = t * 8 + k;
        int d = key >> 8;
        exs[key] = poff[d] + (exs[key] - sstart[d]);
        hist[key] = 0;
    }
    __syncthreads();
    for (int i = t; i < count; i += 256) {
        int p = pairs[base + i];
        int key = (((p & 255) >> 5) << 8) | ((p >> 17) & 255);
        int pos = exs[key] + atomicAdd(&hist[key], 1);
        csr[base + pos] = ((p >> 8) << 7) | (p & 31);   // (src<<7)|dl5
    }
    for (int d = 0; d < 8; ++d) {
        int padded = (dtot[d] + 31) & ~31;
        for (int i = dtot[d] + t; i < padded; i += 256)
            csr[base + poff[d] + i] = (NN << 7);        // gathers zeroed row NN
    }
    if (t < 8) {
        sb_beg[b * 8 + t] = base + poff[t];
        sb_cnt[b * 8 + t] = (dtot[t] + 31) & ~31;
    }
}

// ---- C. pack W1/W2 into per-lane MFMA B-fragments (f16); zero pad rows NN ----
__global__ __launch_bounds__(256) void k_wprep(const float* __restrict__ W1,
                                               const float* __restrict__ W2,
                                               _Float16* __restrict__ w1f,
                                               _Float16* __restrict__ w2f,
                                               short* __restrict__ h1s,
                                               short* __restrict__ hhs) {
    int t = threadIdx.x;
    for (int it = t; it < 16 * 64; it += 256) {   // W1: kk 0..3 x n 0..3
        int f = it >> 6, l = it & 63;
        int kk = f >> 2, n = f & 3;
        int krow = kk * 32 + (l >> 4) * 8;
        int col  = n * 16 + (l & 15);
        #pragma unroll
        for (int i = 0; i < 8; ++i)
            w1f[it * 8 + i] = (_Float16)W1[(krow + i) * HID + col];
    }
    for (int it = t; it < 6 * 64; it += 256) {    // W2: kk 0..1 x n 0..2 (48-col pad)
        int f = it >> 6, l = it & 63;
        int kk = f / 3, n = f - kk * 3;
        int krow = kk * 32 + (l >> 4) * 8;
        int col  = n * 16 + (l & 15);
        #pragma unroll
        for (int i = 0; i < 8; ++i)
            w2f[it * 8 + i] = (col < OUTD) ? (_Float16)W2[(krow + i) * OUTD + col]
                                           : (_Float16)0.f;
    }
    if (t < HID) {                                 // zero the padding row NN
        h1s[(size_t)NN * HID + t] = 0;
        hhs[(size_t)NN * HID + t] = 0;
    }
}

// ---- D. h1s = i16((x @ W1) * dinv[row] * S1) via MFMA ----
__global__ __launch_bounds__(256) void k_mgemm1(const float* __restrict__ x,
                                                const _Float16* __restrict__ w1f,
                                                const float* __restrict__ dinv,
                                                short* __restrict__ h1s) {
    int wid = (blockIdx.x * 256 + threadIdx.x) >> 6;
    int l = threadIdx.x & 63;
    if (wid >= NN / 16) return;
    half8 bf[4][4];
    #pragma unroll
    for (int kk = 0; kk < 4; ++kk)
        #pragma unroll
        for (int n = 0; n < 4; ++n)
            bf[kk][n] = ((const half8*)w1f)[(kk * 4 + n) * 64 + l];
    f32x4 acc[4] = {};
    int arow = wid * 16 + (l & 15);
    const float* xp = x + (size_t)arow * FEAT + (l >> 4) * 8;
    #pragma unroll
    for (int kk = 0; kk < 4; ++kk) {
        float4 u0 = *(const float4*)(xp + kk * 32);
        float4 u1 = *(const float4*)(xp + kk * 32 + 4);
        half8 af;
        af[0] = (_Float16)u0.x; af[1] = (_Float16)u0.y;
        af[2] = (_Float16)u0.z; af[3] = (_Float16)u0.w;
        af[4] = (_Float16)u1.x; af[5] = (_Float16)u1.y;
        af[6] = (_Float16)u1.z; af[7] = (_Float16)u1.w;
        #pragma unroll
        for (int n = 0; n < 4; ++n)
            acc[n] = __builtin_amdgcn_mfma_f32_16x16x32_f16(af, bf[kk][n], acc[n], 0, 0, 0);
    }
    int orow = wid * 16 + (l >> 4) * 4;
    int ocol = l & 15;
    float dv[4];
    #pragma unroll
    for (int r = 0; r < 4; ++r) dv[r] = dinv[orow + r] * S1;
    #pragma unroll
    for (int n = 0; n < 4; ++n)
        #pragma unroll
        for (int r = 0; r < 4; ++r)
            h1s[(size_t)(orow + r) * HID + n * 16 + ocol] =
                (short)__float2int_rn(acc[n][r] * dv[r]);
}

// ---- E. block-per-subbucket edge sweep: short gathers -> LDS int atomicAdd, unroll 32.
// MODE 0: hhs = i16(relu((acc+self)*S1INV*di + b1) * mask * di * S2)
// MODE 1: out = ((acc+self)*S2INV*di) @ W2 + b2  (staged aggf + MFMA in-block)
template<int MODE>
__global__ __launch_bounds__(256) void k_bagg(const int* __restrict__ csr,
                                              const int* __restrict__ sb_beg,
                                              const int* __restrict__ sb_cnt,
                                              const float* __restrict__ dinv,
                                              const short* __restrict__ feat,
                                              const float* __restrict__ b1,
                                              const float* __restrict__ mask,
                                              short* __restrict__ outp,
                                              const _Float16* __restrict__ w2f,
                                              const float* __restrict__ b2,
                                              float* __restrict__ outf) {
    __shared__ int acc[BNODES * HID];     // 8 KB
    int t = threadIdx.x, wv = t >> 6, l = t & 63;
    int bb = blockIdx.x;
    int4* a4 = (int4*)acc;
    for (int i = t; i < BNODES * HID / 4; i += 256) a4[i] = make_int4(0, 0, 0, 0);
    __syncthreads();
    int base  = sb_beg[bb];
    int count = sb_cnt[bb];               // multiple of 32
    int node0 = (bb >> 3) * 256 + (bb & 7) * 32;
    const char* fb = (const char*)feat + ((size_t)l * 2);
    for (int j = wv * 32; j < count; j += 128) {
        int e[32];
        #pragma unroll
        for (int i = 0; i < 32; ++i) e[i] = csr[base + j + i];
        int v[32];
        #pragma unroll
        for (int i = 0; i < 32; ++i)
            v[i] = (int)*(const short*)(fb + (unsigned)(e[i] & ~127));
        #pragma unroll
        for (int i = 0; i < 32; ++i)
            atomicAdd(&acc[((e[i] & 31) << 6) + l], v[i]);
    }
    __syncthreads();
    if constexpr (MODE == 0) {
        for (int n = wv; n < BNODES; n += 4) {
            int node = node0 + n;
            if (node >= NN) break;
            float di = dinv[node];
            int selfv = (int)feat[(size_t)node * HID + l];
            float vv = (float)(acc[(n << 6) + l] + selfv) * S1INV * di;
            vv += b1[l];
            vv = vv > 0.f ? vv : 0.f;
            vv *= mask[(size_t)node * HID + l] * di;
            outp[(size_t)node * HID + l] = (short)__float2int_rn(vv * S2);
        }
    } else {
        __shared__ _Float16 aggf[BNODES][72];   // padded stride 144 B
        for (int n = wv; n < BNODES; n += 4) {
            int node = node0 + n;
            float v = 0.f;
            if (node < NN) {
                float di = dinv[node];
                int selfv = (int)feat[(size_t)node * HID + l];
                v = (float)(acc[(n << 6) + l] + selfv) * S2INV * di;
            }
            aggf[n][l] = (_Float16)v;
        }
        __syncthreads();
        if (wv < 2) {                     // 2 waves x 16 rows = 32 nodes
            half8 bf[2][3];
            #pragma unroll
            for (int kk = 0; kk < 2; ++kk)
                #pragma unroll
                for (int n = 0; n < 3; ++n)
                    bf[kk][n] = ((const half8*)w2f)[(kk * 3 + n) * 64 + l];
            int lrow = wv * 16 + (l & 15);
            int k0 = (l >> 4) * 8;
            f32x4 o[3] = {};
            #pragma unroll
            for (int kk = 0; kk < 2; ++kk) {
                half8 af = *(const half8*)&aggf[lrow][kk * 32 + k0];
                #pragma unroll
                for (int n = 0; n < 3; ++n)
                    o[n] = __builtin_amdgcn_mfma_f32_16x16x32_f16(af, bf[kk][n], o[n], 0, 0, 0);
            }
            int orow = node0 + wv * 16 + (l >> 4) * 4;
            int ocol = l & 15;
            #pragma unroll
            for (int n = 0; n < 3; ++n) {
                int col = n * 16 + ocol;
                if (col < OUTD) {
                    float bbias = b2[col];
                    #pragma unroll
                    for (int r = 0; r < 4; ++r) {
                        int row = orow + r;
                        if (row < NN)
                            outf[(size_t)row * OUTD + col] = o[n][r] + bbias;
                    }
                }
            }
        }
    }
}

extern "C" void kernel_launch(void* const* d_in, const int* in_sizes, int n_in,
                              void* d_out, int out_size, void* d_ws, size_t ws_size,
                              hipStream_t stream) {
    const float* x    = (const float*)d_in[0];
    const int*   ei   = (const int*)d_in[1];
    const int*   src  = ei;
    const int*   dst  = ei + NE;
    const float* W1   = (const float*)d_in[2];
    const float* b1   = (const float*)d_in[3];
    const float* W2   = (const float*)d_in[4];
    const float* b2   = (const float*)d_in[5];
    const float* mask = (const float*)d_in[6];
    float* out = (float*)d_out;

    char* ws = (char*)d_ws;
    int*      bfill  = (int*)ws;           ws += (size_t)NSB * 4;
    int*      sb_beg = (int*)ws;           ws += (size_t)NBAGG * 4;
    int*      sb_cnt = (int*)ws;           ws += (size_t)NBAGG * 4;
    float*    dinv   = (float*)ws;         ws += (size_t)NN * 4;
    _Float16* w1f    = (_Float16*)ws;      ws += 16 * 64 * 8 * 2;
    _Float16* w2f    = (_Float16*)ws;      ws += 6 * 64 * 8 * 2;
    int*      csr    = (int*)ws;           ws += (size_t)NSB * CAP * 4;       // 8.0 MB
    short*    h1s    = (short*)ws;         ws += (size_t)(NN + 1) * HID * 2;  // 12.8 MB
    short*    hhs    = (short*)ws;         ws += (size_t)(NN + 1) * HID * 2;  // 12.8 MB
    int*      pairs  = (int*)hhs;          // alias: pairs (8 MB) dead before hhs written

    hipMemsetAsync(bfill, 0, (size_t)NSB * 4, stream);

    k_pairs <<<(NE + CCHUNK - 1) / CCHUNK, 256, 0, stream>>>(src, dst, bfill, pairs);
    k_csr   <<<NSB, 256, 0, stream>>>(pairs, bfill, sb_beg, sb_cnt, csr, dinv);
    k_wprep <<<1, 256, 0, stream>>>(W1, W2, w1f, w2f, h1s, hhs);

    k_mgemm1<<<(NN / 16 + 3) / 4, 256, 0, stream>>>(x, w1f, dinv, h1s);
    k_bagg<0><<<NBAGG, 256, 0, stream>>>(csr, sb_beg, sb_cnt, dinv, h1s, b1, mask,
                                         hhs, nullptr, nullptr, nullptr);
    k_bagg<1><<<NBAGG, 256, 0, stream>>>(csr, sb_beg, sb_cnt, dinv, hhs, nullptr, nullptr,
                                         nullptr, w2f, b2, out);
}

// Round 21
// 164.536 us; speedup vs baseline: 1.0687x; 1.0687x over previous
//
#include <hip/hip_runtime.h>
#include <hip/hip_fp16.h>

#define NN     100000
#define NE     1600000
#define FEAT   128
#define HID    64
#define OUTD   40
#define BNODES 32                         // aggregation bucket = 32 dst nodes
#define NSB    ((NN + 255) / 256)         // 391 superbuckets of 256 nodes
#define NBAGG  (NSB * 8)                  // 3128 aggregation buckets
#define CAP    5120                       // superbucket capacity (mean 4096, sd ~64)
#define CCHUNK 4096                       // edges per block in pair-scatter (mult of 4)
#define S1     4096.0f                    // h1s fixed-point scale (2^12)
#define S1INV  (1.0f / 4096.0f)
#define S2     2048.0f                    // hhs fixed-point scale (2^11)
#define S2INV  (1.0f / 2048.0f)

typedef _Float16 half8 __attribute__((ext_vector_type(8)));
typedef float    f32x4 __attribute__((ext_vector_type(4)));

// ---- A. scatter packed ex=(src<<8|dl) into superbucket segments (int4 loads) ----
__global__ __launch_bounds__(256) void k_pairs(const int* __restrict__ src,
                                               const int* __restrict__ dst,
                                               int* __restrict__ bfill,
                                               int* __restrict__ pairs) {
    __shared__ int bcnt[NSB];
    __shared__ int gb[NSB];
    int t = threadIdx.x;
    for (int i = t; i < NSB; i += 256) bcnt[i] = 0;
    __syncthreads();
    const int4* d4p = (const int4*)dst;
    const int4* s4p = (const int4*)src;
    int q0 = blockIdx.x * (CCHUNK / 4);
    int4 dv[4], sv[4];
    int off[16];
    #pragma unroll
    for (int i = 0; i < 4; ++i) {
        int q = q0 + i * 256 + t;
        if (q < NE / 4) {
            dv[i] = d4p[q];
            sv[i] = s4p[q];
            off[i*4+0] = atomicAdd(&bcnt[dv[i].x >> 8], 1);
            off[i*4+1] = atomicAdd(&bcnt[dv[i].y >> 8], 1);
            off[i*4+2] = atomicAdd(&bcnt[dv[i].z >> 8], 1);
            off[i*4+3] = atomicAdd(&bcnt[dv[i].w >> 8], 1);
        } else dv[i].x = -1;
    }
    __syncthreads();
    for (int i = t; i < NSB; i += 256) {
        int c = bcnt[i];
        gb[i] = c ? (i * CAP + atomicAdd(&bfill[i], c)) : 0;
    }
    __syncthreads();
    #pragma unroll
    for (int i = 0; i < 4; ++i) {
        if (dv[i].x >= 0) {
            pairs[gb[dv[i].x >> 8] + off[i*4+0]] = (sv[i].x << 8) | (dv[i].x & 255);
            pairs[gb[dv[i].y >> 8] + off[i*4+1]] = (sv[i].y << 8) | (dv[i].y & 255);
            pairs[gb[dv[i].z >> 8] + off[i*4+2]] = (sv[i].z << 8) | (dv[i].z & 255);
            pairs[gb[dv[i].w >> 8] + off[i*4+3]] = (sv[i].w << 8) | (dv[i].w & 255);
        }
    }
}

// ---- B. per-superbucket counting sort by (subbucket, src-stripe) + per-node dinv ----
__global__ __launch_bounds__(256) void k_csr(const int* __restrict__ pairs,
                                             const int* __restrict__ bfill,
                                             int* __restrict__ sb_beg,
                                             int* __restrict__ sb_cnt,
                                             int* __restrict__ csr,
                                             float* __restrict__ dinv) {
    __shared__ int hist[2048];
    __shared__ int exs[2048];
    __shared__ int nd[256];
    __shared__ int part[256];
    __shared__ int poff[9];
    __shared__ int sstart[8];
    __shared__ int dtot[8];
    int b = blockIdx.x, t = threadIdx.x;
    #pragma unroll
    for (int k = 0; k < 8; ++k) hist[t * 8 + k] = 0;
    nd[t] = 0;
    __syncthreads();
    int base = b * CAP, count = bfill[b];
    for (int i = t; i < count; i += 256) {
        int p = pairs[base + i];
        int key = (((p & 255) >> 5) << 8) | ((p >> 17) & 255);
        atomicAdd(&hist[key], 1);
        atomicAdd(&nd[p & 255], 1);
    }
    __syncthreads();
    {
        int node = (b << 8) + t;
        if (node < NN) dinv[node] = rsqrtf((float)nd[t] + 1.0f);
    }
    int loc[8], s0 = 0;
    #pragma unroll
    for (int k = 0; k < 8; ++k) { loc[k] = s0; s0 += hist[t * 8 + k]; }
    part[t] = s0;
    __syncthreads();
    for (int off = 1; off < 256; off <<= 1) {
        int u = (t >= off) ? part[t - off] : 0;
        __syncthreads();
        part[t] += u;
        __syncthreads();
    }
    int pex = part[t] - s0;
    #pragma unroll
    for (int k = 0; k < 8; ++k) exs[t * 8 + k] = pex + loc[k];
    __syncthreads();
    if (t < 8) {
        sstart[t] = exs[t * 256];
        int end = (t == 7) ? count : exs[(t + 1) * 256];
        dtot[t] = end - sstart[t];
    }
    __syncthreads();
    if (t == 0) {
        poff[0] = 0;
        for (int d = 0; d < 8; ++d) poff[d + 1] = poff[d] + ((dtot[d] + 31) & ~31);
    }
    __syncthreads();
    #pragma unroll
    for (int k = 0; k < 8; ++k) {
        int key = t * 8 + k;
        int d = key >> 8;
        exs[key] = poff[d] + (exs[key] - sstart[d]);
        hist[key] = 0;
    }
    __syncthreads();
    for (int i = t; i < count; i += 256) {
        int p = pairs[base + i];
        int key = (((p & 255) >> 5) << 8) | ((p >> 17) & 255);
        int pos = exs[key] + atomicAdd(&hist[key], 1);
        csr[base + pos] = ((p >> 8) << 7) | (p & 31);   // (src<<7)|dl5
    }
    for (int d = 0; d < 8; ++d) {
        int padded = (dtot[d] + 31) & ~31;
        for (int i = dtot[d] + t; i < padded; i += 256)
            csr[base + poff[d] + i] = (NN << 7);        // gathers zeroed row NN
    }
    if (t < 8) {
        sb_beg[b * 8 + t] = base + poff[t];
        sb_cnt[b * 8 + t] = (dtot[t] + 31) & ~31;
    }
}

// ---- C. pack W1/W2 into per-lane MFMA B-fragments (f16); zero pad rows NN ----
__global__ __launch_bounds__(256) void k_wprep(const float* __restrict__ W1,
                                               const float* __restrict__ W2,
                                               _Float16* __restrict__ w1f,
                                               _Float16* __restrict__ w2f,
                                               short* __restrict__ h1s,
                                               short* __restrict__ hhs) {
    int t = threadIdx.x;
    for (int it = t; it < 16 * 64; it += 256) {   // W1: kk 0..3 x n 0..3
        int f = it >> 6, l = it & 63;
        int kk = f >> 2, n = f & 3;
        int krow = kk * 32 + (l >> 4) * 8;
        int col  = n * 16 + (l & 15);
        #pragma unroll
        for (int i = 0; i < 8; ++i)
            w1f[it * 8 + i] = (_Float16)W1[(krow + i) * HID + col];
    }
    for (int it = t; it < 6 * 64; it += 256) {    // W2: kk 0..1 x n 0..2 (48-col pad)
        int f = it >> 6, l = it & 63;
        int kk = f / 3, n = f - kk * 3;
        int krow = kk * 32 + (l >> 4) * 8;
        int col  = n * 16 + (l & 15);
        #pragma unroll
        for (int i = 0; i < 8; ++i)
            w2f[it * 8 + i] = (col < OUTD) ? (_Float16)W2[(krow + i) * OUTD + col]
                                           : (_Float16)0.f;
    }
    if (t < HID) {                                 // zero the padding row NN
        h1s[(size_t)NN * HID + t] = 0;
        hhs[(size_t)NN * HID + t] = 0;
    }
}

// ---- D. h1s = i16((x @ W1) * dinv[row] * S1) via MFMA ----
__global__ __launch_bounds__(256) void k_mgemm1(const float* __restrict__ x,
                                                const _Float16* __restrict__ w1f,
                                                const float* __restrict__ dinv,
                                                short* __restrict__ h1s) {
    int wid = (blockIdx.x * 256 + threadIdx.x) >> 6;
    int l = threadIdx.x & 63;
    if (wid >= NN / 16) return;
    half8 bf[4][4];
    #pragma unroll
    for (int kk = 0; kk < 4; ++kk)
        #pragma unroll
        for (int n = 0; n < 4; ++n)
            bf[kk][n] = ((const half8*)w1f)[(kk * 4 + n) * 64 + l];
    f32x4 acc[4] = {};
    int arow = wid * 16 + (l & 15);
    const float* xp = x + (size_t)arow * FEAT + (l >> 4) * 8;
    #pragma unroll
    for (int kk = 0; kk < 4; ++kk) {
        float4 u0 = *(const float4*)(xp + kk * 32);
        float4 u1 = *(const float4*)(xp + kk * 32 + 4);
        half8 af;
        af[0] = (_Float16)u0.x; af[1] = (_Float16)u0.y;
        af[2] = (_Float16)u0.z; af[3] = (_Float16)u0.w;
        af[4] = (_Float16)u1.x; af[5] = (_Float16)u1.y;
        af[6] = (_Float16)u1.z; af[7] = (_Float16)u1.w;
        #pragma unroll
        for (int n = 0; n < 4; ++n)
            acc[n] = __builtin_amdgcn_mfma_f32_16x16x32_f16(af, bf[kk][n], acc[n], 0, 0, 0);
    }
    int orow = wid * 16 + (l >> 4) * 4;
    int ocol = l & 15;
    float dv[4];
    #pragma unroll
    for (int r = 0; r < 4; ++r) dv[r] = dinv[orow + r] * S1;
    #pragma unroll
    for (int n = 0; n < 4; ++n)
        #pragma unroll
        for (int r = 0; r < 4; ++r)
            h1s[(size_t)(orow + r) * HID + n * 16 + ocol] =
                (short)__float2int_rn(acc[n][r] * dv[r]);
}

// ---- E. block-per-subbucket edge sweep: short gathers -> LDS int atomicAdd (no cvt).
// MODE 0: hhs = i16(relu((acc+self)*S1INV*di + b1) * mask * di * S2)
// MODE 1: out = ((acc+self)*S2INV*di) @ W2 + b2  (staged aggf + MFMA in-block)
template<int MODE>
__global__ __launch_bounds__(256) void k_bagg(const int* __restrict__ csr,
                                              const int* __restrict__ sb_beg,
                                              const int* __restrict__ sb_cnt,
                                              const float* __restrict__ dinv,
                                              const short* __restrict__ feat,
                                              const float* __restrict__ b1,
                                              const float* __restrict__ mask,
                                              short* __restrict__ outp,
                                              const _Float16* __restrict__ w2f,
                                              const float* __restrict__ b2,
                                              float* __restrict__ outf) {
    __shared__ int acc[BNODES * HID];     // 8 KB
    int t = threadIdx.x, wv = t >> 6, l = t & 63;
    int bb = blockIdx.x;
    int4* a4 = (int4*)acc;
    for (int i = t; i < BNODES * HID / 4; i += 256) a4[i] = make_int4(0, 0, 0, 0);
    __syncthreads();
    int base  = sb_beg[bb];
    int count = sb_cnt[bb];               // multiple of 32
    int node0 = (bb >> 3) * 256 + (bb & 7) * 32;
    const char* fb = (const char*)feat + ((size_t)l * 2);
    for (int j = wv * 16; j < count; j += 64) {
        int e[16];
        #pragma unroll
        for (int i = 0; i < 16; ++i) e[i] = csr[base + j + i];
        int v[16];
        #pragma unroll
        for (int i = 0; i < 16; ++i)
            v[i] = (int)*(const short*)(fb + (unsigned)(e[i] & ~127));
        #pragma unroll
        for (int i = 0; i < 16; ++i)
            atomicAdd(&acc[((e[i] & 31) << 6) + l], v[i]);
    }
    __syncthreads();
    if constexpr (MODE == 0) {
        for (int n = wv; n < BNODES; n += 4) {
            int node = node0 + n;
            if (node >= NN) break;
            float di = dinv[node];
            int selfv = (int)feat[(size_t)node * HID + l];
            float vv = (float)(acc[(n << 6) + l] + selfv) * S1INV * di;
            vv += b1[l];
            vv = vv > 0.f ? vv : 0.f;
            vv *= mask[(size_t)node * HID + l] * di;
            outp[(size_t)node * HID + l] = (short)__float2int_rn(vv * S2);
        }
    } else {
        __shared__ _Float16 aggf[BNODES][72];   // padded stride 144 B
        for (int n = wv; n < BNODES; n += 4) {
            int node = node0 + n;
            float v = 0.f;
            if (node < NN) {
                float di = dinv[node];
                int selfv = (int)feat[(size_t)node * HID + l];
                v = (float)(acc[(n << 6) + l] + selfv) * S2INV * di;
            }
            aggf[n][l] = (_Float16)v;
        }
        __syncthreads();
        if (wv < 2) {                     // 2 waves x 16 rows = 32 nodes
            half8 bf[2][3];
            #pragma unroll
            for (int kk = 0; kk < 2; ++kk)
                #pragma unroll
                for (int n = 0; n < 3; ++n)
                    bf[kk][n] = ((const half8*)w2f)[(kk * 3 + n) * 64 + l];
            int lrow = wv * 16 + (l & 15);
            int k0 = (l >> 4) * 8;
            f32x4 o[3] = {};
            #pragma unroll
            for (int kk = 0; kk < 2; ++kk) {
                half8 af = *(const half8*)&aggf[lrow][kk * 32 + k0];
                #pragma unroll
                for (int n = 0; n < 3; ++n)
                    o[n] = __builtin_amdgcn_mfma_f32_16x16x32_f16(af, bf[kk][n], o[n], 0, 0, 0);
            }
            int orow = node0 + wv * 16 + (l >> 4) * 4;
            int ocol = l & 15;
            #pragma unroll
            for (int n = 0; n < 3; ++n) {
                int col = n * 16 + ocol;
                if (col < OUTD) {
                    float bbias = b2[col];
                    #pragma unroll
                    for (int r = 0; r < 4; ++r) {
                        int row = orow + r;
                        if (row < NN)
                            outf[(size_t)row * OUTD + col] = o[n][r] + bbias;
                    }
                }
            }
        }
    }
}

extern "C" void kernel_launch(void* const* d_in, const int* in_sizes, int n_in,
                              void* d_out, int out_size, void* d_ws, size_t ws_size,
                              hipStream_t stream) {
    const float* x    = (const float*)d_in[0];
    const int*   ei   = (const int*)d_in[1];
    const int*   src  = ei;
    const int*   dst  = ei + NE;
    const float* W1   = (const float*)d_in[2];
    const float* b1   = (const float*)d_in[3];
    const float* W2   = (const float*)d_in[4];
    const float* b2   = (const float*)d_in[5];
    const float* mask = (const float*)d_in[6];
    float* out = (float*)d_out;

    char* ws = (char*)d_ws;
    int*      bfill  = (int*)ws;           ws += (size_t)NSB * 4;
    int*      sb_beg = (int*)ws;           ws += (size_t)NBAGG * 4;
    int*      sb_cnt = (int*)ws;           ws += (size_t)NBAGG * 4;
    float*    dinv   = (float*)ws;         ws += (size_t)NN * 4;
    _Float16* w1f    = (_Float16*)ws;      ws += 16 * 64 * 8 * 2;
    _Float16* w2f    = (_Float16*)ws;      ws += 6 * 64 * 8 * 2;
    int*      csr    = (int*)ws;           ws += (size_t)NSB * CAP * 4;       // 8.0 MB
    short*    h1s    = (short*)ws;         ws += (size_t)(NN + 1) * HID * 2;  // 12.8 MB
    short*    hhs    = (short*)ws;         ws += (size_t)(NN + 1) * HID * 2;  // 12.8 MB
    int*      pairs  = (int*)hhs;          // alias: pairs (8 MB) dead before hhs written

    hipMemsetAsync(bfill, 0, (size_t)NSB * 4, stream);

    k_pairs <<<(NE + CCHUNK - 1) / CCHUNK, 256, 0, stream>>>(src, dst, bfill, pairs);
    k_csr   <<<NSB, 256, 0, stream>>>(pairs, bfill, sb_beg, sb_cnt, csr, dinv);
    k_wprep <<<1, 256, 0, stream>>>(W1, W2, w1f, w2f, h1s, hhs);

    k_mgemm1<<<(NN / 16 + 3) / 4, 256, 0, stream>>>(x, w1f, dinv, h1s);
    k_bagg<0><<<NBAGG, 256, 0, stream>>>(csr, sb_beg, sb_cnt, dinv, h1s, b1, mask,
                                         hhs, nullptr, nullptr, nullptr);
    k_bagg<1><<<NBAGG, 256, 0, stream>>>(csr, sb_beg, sb_cnt, dinv, hhs, nullptr, nullptr,
                                         nullptr, w2f, b2, out);
}